// Round 1
// baseline (412.890 us; speedup 1.0000x reference)
//
#include <hip/hip_runtime.h>
#include <cstdint>
#include <cstddef>

// Problem constants (fixed by reference).
#define BATCH 16
#define SEQ   4096
#define DI    64
#define DO    64
#define NS    512
#define TLAG  192            // truncation: ||A^192|| ~ 0.9^192 ~ 6e-10
#define PADR  192            // zero left-pad rows in padded x buffer
#define PS    (SEQ + PADR)   // 4288 padded rows per batch

typedef unsigned short u16;
typedef unsigned int   u32;
typedef short bf16x8 __attribute__((ext_vector_type(8)));   // 8 bf16 = 4 VGPRs
typedef float f32x4  __attribute__((ext_vector_type(4)));   // MFMA accumulator

__device__ __forceinline__ u16 f2bf(float f) {
    u32 u = __builtin_bit_cast(u32, f);
    return (u16)((u + 0x7FFFu + ((u >> 16) & 1u)) >> 16);   // RNE
}
__device__ __forceinline__ float bf2f(u16 h) {
    return __builtin_bit_cast(float, (u32)h << 16);
}

// ---------------------------------------------------------------------------
// prep_x: x fp32 [16,4096,64] -> xbf bf16 [16, 4288, 64] with 192 zero rows
// prepended per batch (so conv never branches on the left boundary).
// ---------------------------------------------------------------------------
__global__ __launch_bounds__(256) void prep_x(const float* __restrict__ x,
                                              u16* __restrict__ xbf)
{
    const int id = blockIdx.x * 256 + threadIdx.x;   // 16*4288*16 = 1,097,728
    const int b   = id / (PS * 16);
    const int rem = id - b * (PS * 16);
    const int p   = rem >> 4;
    const int g   = id & 15;

    ushort4 o;
    if (p < PADR) {
        o.x = 0; o.y = 0; o.z = 0; o.w = 0;
    } else {
        const float4 v = *(const float4*)(x + ((size_t)b * SEQ + (p - PADR)) * 64 + g * 4);
        o.x = f2bf(v.x); o.y = f2bf(v.y); o.z = f2bf(v.z); o.w = f2bf(v.w);
    }
    *(ushort4*)(xbf + ((size_t)b * PS + p) * 64 + g * 4) = o;
}

// ---------------------------------------------------------------------------
// prep_mats: A -> Ap0 (row-major bf16) and ApT0 (transposed bf16);
//            B -> KstT lag-0 block (KstT[c=i][k] = B[k][i]); C -> Cbf.
// ---------------------------------------------------------------------------
__global__ __launch_bounds__(256) void prep_mats(const float* __restrict__ A,
                                                 const float* __restrict__ B,
                                                 const float* __restrict__ C,
                                                 u16* __restrict__ Ap0,
                                                 u16* __restrict__ ApT0,
                                                 u16* __restrict__ Kst0T,
                                                 u16* __restrict__ Cbf)
{
    const int id = blockIdx.x * 256 + threadIdx.x;   // 327,680 total
    if (id < 262144) {                                // A: 512x512
        const int r = id >> 9, c = id & 511;
        const u16 v = f2bf(A[id]);
        Ap0[id] = v;
        ApT0[(size_t)c * 512 + r] = v;
    } else if (id < 262144 + 32768) {                 // B: 512x64 -> transpose
        const int i = id - 262144;
        const int k = i >> 6, c = i & 63;
        Kst0T[(size_t)c * 512 + k] = f2bf(B[i]);
    } else if (id < 262144 + 32768 + 32768) {         // C: 64x512 row-major
        const int i = id - 262144 - 32768;
        Cbf[i] = f2bf(C[i]);
    }
}

// ---------------------------------------------------------------------------
// gemm_bt: out[M,N] = Aop[M,512] @ BopT[N,512]^T   (K = 512 fixed, bf16 in,
// fp32 accum, bf16 out). BopT is B stored transposed so B-fragments are
// contiguous 16B loads. Optional row-major and/or transposed outputs.
// grid = (N/64, M/64), block = 256 (4 waves, 16 rows each).
// ---------------------------------------------------------------------------
__global__ __launch_bounds__(256, 1) void gemm_bt(const u16* __restrict__ Aop, int lda,
                                                  const u16* __restrict__ BopT, int ldbt,
                                                  u16* __restrict__ outRM, int ldo,
                                                  u16* __restrict__ outT, int ldoT)
{
    const int tid = threadIdx.x;
    const int w = tid >> 6, l = tid & 63;
    const int lr = l & 15, q8 = (l >> 4) * 8;
    const int m0 = blockIdx.y * 64 + w * 16;
    const int n0 = blockIdx.x * 64;

    const u16* ap  = Aop  + (size_t)(m0 + lr) * lda  + q8;
    const u16* bp0 = BopT + (size_t)(n0 + lr) * ldbt + q8;

    f32x4 acc[4];
    const f32x4 zero = {0.f, 0.f, 0.f, 0.f};
    #pragma unroll
    for (int nt = 0; nt < 4; ++nt) acc[nt] = zero;

    #pragma unroll 4
    for (int ks = 0; ks < 16; ++ks) {
        const bf16x8 a = *(const bf16x8*)(ap + ks * 32);
        #pragma unroll
        for (int nt = 0; nt < 4; ++nt) {
            const bf16x8 bfr = *(const bf16x8*)(bp0 + (size_t)nt * 16 * ldbt + ks * 32);
            acc[nt] = __builtin_amdgcn_mfma_f32_16x16x32_bf16(a, bfr, acc[nt], 0, 0, 0);
        }
    }

    const int rr = (l >> 4) * 4;    // C/D: row = (lane>>4)*4 + reg, col = lane&15
    #pragma unroll
    for (int nt = 0; nt < 4; ++nt) {
        const int col = n0 + nt * 16 + lr;
        if (outRM) {
            #pragma unroll
            for (int r = 0; r < 4; ++r)
                outRM[(size_t)(m0 + rr + r) * ldo + col] = f2bf(acc[nt][r]);
        }
        if (outT) {
            ushort4 pk;
            pk.x = f2bf(acc[nt][0]); pk.y = f2bf(acc[nt][1]);
            pk.z = f2bf(acc[nt][2]); pk.w = f2bf(acc[nt][3]);
            *(ushort4*)(outT + (size_t)col * ldoT + m0 + rr) = pk;
        }
    }
}

// ---------------------------------------------------------------------------
// repack_g: GtmpT[m*64+i][o] = G_m[o][i]  ->  Gsw in exact B-fragment order:
// frag fi = m*8 + ks*4 + nt; lane l holds 8 bf16: G_m[o = nt*16+(l&15)]
// [i = ks*32+(l>>4)*8+j]. Folds D into the lag-0 kernel (y += D x).
// ---------------------------------------------------------------------------
__global__ __launch_bounds__(256) void repack_g(const u16* __restrict__ GtmpT,
                                                const float* __restrict__ D,
                                                u16* __restrict__ Gsw)
{
    const int id = blockIdx.x * 256 + threadIdx.x;  // 192*8*64 = 98,304
    const int l  = id & 63;
    const int fi = id >> 6;
    const int m  = fi >> 3;
    const int ks = (fi >> 2) & 1;
    const int nt = fi & 3;
    const int o  = nt * 16 + (l & 15);
    const int q8 = (l >> 4) * 8;

    u16 v[8];
    #pragma unroll
    for (int j = 0; j < 8; ++j) {
        const int i = ks * 32 + q8 + j;
        u16 g = GtmpT[(size_t)(m * 64 + i) * 64 + o];
        if (m == 0) g = f2bf(bf2f(g) + D[o * 64 + i]);
        v[j] = g;
    }
    ushort4* dst = (ushort4*)(Gsw + (size_t)id * 8);
    ushort4 p0; p0.x = v[0]; p0.y = v[1]; p0.z = v[2]; p0.w = v[3];
    ushort4 p1; p1.x = v[4]; p1.y = v[5]; p1.z = v[6]; p1.w = v[7];
    dst[0] = p0; dst[1] = p1;
}

// ---------------------------------------------------------------------------
// conv_kernel: y[b, t0+tau, o] = sum_{m=0}^{191} sum_i G_m[o][i] x[t0+tau-m][i]
// Grid (16 time-tiles, 16 batches); 256 threads = 4 waves x 64 rows.
// X tile (256 rows + 191 halo) in LDS, stride 72 (bank-balanced b128 reads).
// G fragments streamed from L2 with a 1-lag register prefetch.
// ---------------------------------------------------------------------------
__global__ __launch_bounds__(256, 1) void conv_kernel(const u16* __restrict__ xbf,
                                                      const u16* __restrict__ gsw,
                                                      float* __restrict__ y)
{
    __shared__ u16 Xs[448 * 72];   // 64,512 B

    const int tid = threadIdx.x;
    const int b  = blockIdx.y;
    const int t0 = blockIdx.x * 256;

    // Stage X rows [t0-191 .. t0+255] (padded index t0+1 .. t0+447) into LDS.
    {
        const int g = tid & 7;
        int r = tid >> 3;
        const u16* src = xbf + ((size_t)b * PS + t0 + 1) * 64 + g * 8;
        #pragma unroll
        for (int it = 0; it < 14; ++it, r += 32) {
            if (r < 447) {
                const uint4 v = *(const uint4*)(src + (size_t)r * 64);
                *(uint4*)&Xs[r * 72 + g * 8] = v;
            }
        }
    }
    __syncthreads();

    const int w    = tid >> 6;
    const int l    = tid & 63;
    const int lr   = l & 15;
    const int q8   = (l >> 4) * 8;
    const int wrow = w * 64;

    const uint4* gp = (const uint4*)gsw + l;
    uint4 bn[8];
    #pragma unroll
    for (int f = 0; f < 8; ++f) bn[f] = gp[f * 64];

    f32x4 acc[4][4];
    const f32x4 zero = {0.f, 0.f, 0.f, 0.f};
    #pragma unroll
    for (int mt = 0; mt < 4; ++mt)
        #pragma unroll
        for (int nt = 0; nt < 4; ++nt) acc[mt][nt] = zero;

    #pragma unroll 2
    for (int m = 0; m < TLAG; ++m) {
        bf16x8 bc[8];
        #pragma unroll
        for (int f = 0; f < 8; ++f) bc[f] = __builtin_bit_cast(bf16x8, bn[f]);
        if (m < TLAG - 1) {
            const uint4* gn = gp + (size_t)(m + 1) * 512;
            #pragma unroll
            for (int f = 0; f < 8; ++f) bn[f] = gn[f * 64];
        }

        const int rbase = wrow + lr + (TLAG - 1) - m;
        bf16x8 a[4][2];
        #pragma unroll
        for (int mt = 0; mt < 4; ++mt)
            #pragma unroll
            for (int ks = 0; ks < 2; ++ks)
                a[mt][ks] = *(const bf16x8*)&Xs[(rbase + mt * 16) * 72 + ks * 32 + q8];

        #pragma unroll
        for (int ks = 0; ks < 2; ++ks)
            #pragma unroll
            for (int mt = 0; mt < 4; ++mt)
                #pragma unroll
                for (int nt = 0; nt < 4; ++nt)
                    acc[mt][nt] = __builtin_amdgcn_mfma_f32_16x16x32_bf16(
                        a[mt][ks], bc[ks * 4 + nt], acc[mt][nt], 0, 0, 0);
    }

    // Epilogue: C/D layout col = lane&15 (out-feature), row = (lane>>4)*4+reg (time).
    const int rr = (l >> 4) * 4;
    #pragma unroll
    for (int mt = 0; mt < 4; ++mt) {
        #pragma unroll
        for (int nt = 0; nt < 4; ++nt) {
            const int t = t0 + wrow + mt * 16 + rr;
            const int o = nt * 16 + lr;
            float* yp = y + ((size_t)b * SEQ + t) * 64 + o;
            #pragma unroll
            for (int r = 0; r < 4; ++r) yp[(size_t)r * 64] = acc[mt][nt][r];
        }
    }
}

// ---------------------------------------------------------------------------
// Workspace layout (bytes, 16-aligned):
//   0         xbf    8,781,824   (16 x 4288 x 64 bf16)
//   8781824   Ap0      524,288   (A^h row-major, ping)
//   9306112   Ap1      524,288   (pong)
//   9830400   ApT0     524,288   (A^h transposed, ping)
//  10354688   ApT1     524,288   (pong)
//  10878976   KstT  12,582,912   ([192*64][512]: KstT[m*64+i][k] = (A^m B)[k][i])
//  23461888   Cbf       65,536
//  23527424   GtmpT  1,572,864   ([192*64][64]: G_m[o][i] transposed)
//  25100288   Gsw    1,572,864   (B-fragment-swizzled conv kernels)
//  total: 26,673,152
// ---------------------------------------------------------------------------
extern "C" void kernel_launch(void* const* d_in, const int* in_sizes, int n_in,
                              void* d_out, int out_size, void* d_ws, size_t ws_size,
                              hipStream_t stream)
{
    const float* x = (const float*)d_in[0];
    const float* A = (const float*)d_in[1];
    const float* B = (const float*)d_in[2];
    const float* C = (const float*)d_in[3];
    const float* D = (const float*)d_in[4];
    float* y = (float*)d_out;

    char* w = (char*)d_ws;
    u16* xbf   = (u16*)(w + 0);
    u16* Ap[2]  = { (u16*)(w + 8781824),  (u16*)(w + 9306112) };
    u16* ApT[2] = { (u16*)(w + 9830400),  (u16*)(w + 10354688) };
    u16* KstT  = (u16*)(w + 10878976);
    u16* Cbf   = (u16*)(w + 23461888);
    u16* GtmpT = (u16*)(w + 23527424);
    u16* Gsw   = (u16*)(w + 25100288);

    prep_x<<<4288, 256, 0, stream>>>(x, xbf);
    prep_mats<<<1280, 256, 0, stream>>>(A, B, C, Ap[0], ApT[0], KstT, Cbf);

    // Log-depth build of KstT lags [0, 192): K_{h+i} = A^h @ K_i, A^{2h} = A^h A^h.
    int cur = 0, have = 1;
    while (have < TLAG) {
        const int n_new = (have < TLAG - have) ? have : (TLAG - have);
        gemm_bt<<<dim3(n_new, 8), 256, 0, stream>>>(Ap[cur], NS, KstT, NS,
                                                    nullptr, 0,
                                                    KstT + (size_t)have * 64 * NS, NS);
        have += n_new;
        if (have < TLAG) {
            gemm_bt<<<dim3(8, 8), 256, 0, stream>>>(Ap[cur], NS, ApT[cur], NS,
                                                    Ap[cur ^ 1], NS, ApT[cur ^ 1], NS);
            cur ^= 1;
        }
    }

    // G_m = C @ (A^m B)  -> GtmpT [m*64+i][o]
    gemm_bt<<<dim3(TLAG, 1), 256, 0, stream>>>(Cbf, NS, KstT, NS, nullptr, 0, GtmpT, 64);
    repack_g<<<384, 256, 0, stream>>>(GtmpT, D, Gsw);

    conv_kernel<<<dim3(16, 16), 256, 0, stream>>>(xbf, Gsw, y);
}

// Round 2
// 255.252 us; speedup vs baseline: 1.6176x; 1.6176x over previous
//
#include <hip/hip_runtime.h>
#include <cstdint>
#include <cstddef>

// Problem constants (fixed by reference).
#define BATCH 16
#define SEQ   4096
#define NS    512
#define TLAG  128            // truncation: ||A^128|| ~ 1e-5 -> error ~1e-4 << bf16 noise
#define PADR  128            // zero left-pad rows in padded x buffer
#define PS    (SEQ + PADR)   // 4224 padded rows per batch
#define CTILE 128            // conv time-tile rows per block
#define XROWS (CTILE + TLAG - 1)   // 255 staged rows
#define XSTR  72             // LDS row stride in u16 (144 B = 9*16B)

typedef unsigned short u16;
typedef unsigned int   u32;
typedef short bf16x8 __attribute__((ext_vector_type(8)));   // 8 bf16 = 4 VGPRs
typedef float f32x4  __attribute__((ext_vector_type(4)));   // MFMA accumulator

__device__ __forceinline__ u16 f2bf(float f) {
    u32 u = __builtin_bit_cast(u32, f);
    return (u16)((u + 0x7FFFu + ((u >> 16) & 1u)) >> 16);   // RNE
}
__device__ __forceinline__ float bf2f(u16 h) {
    return __builtin_bit_cast(float, (u32)h << 16);
}

// ---------------------------------------------------------------------------
// prep_all: one launch for all input conversion.
//  blocks [0,4224):  x fp32 [16,4096,64] -> xbf bf16 [16,4224,64], 128 zero
//                    rows prepended per batch.
//  blocks [4224,5504): A -> Ap0 (RM bf16) + ApT0 (transposed);
//                      B -> BT (B^T, [64][512]); C -> Wall rows 0..63 (W_0).
// ---------------------------------------------------------------------------
__global__ __launch_bounds__(256) void prep_all(const float* __restrict__ x,
                                                const float* __restrict__ A,
                                                const float* __restrict__ B,
                                                const float* __restrict__ C,
                                                u16* __restrict__ xbf,
                                                u16* __restrict__ Ap0,
                                                u16* __restrict__ ApT0,
                                                u16* __restrict__ BT,
                                                u16* __restrict__ Wall)
{
    const int bid = blockIdx.x;
    if (bid < 4224) {
        const int id = bid * 256 + threadIdx.x;      // 16*4224*16 = 1,081,344
        const int b   = id / (PS * 16);
        const int rem = id - b * (PS * 16);
        const int p   = rem >> 4;
        const int g   = id & 15;
        ushort4 o;
        if (p < PADR) {
            o.x = 0; o.y = 0; o.z = 0; o.w = 0;
        } else {
            const float4 v = *(const float4*)(x + ((size_t)b * SEQ + (p - PADR)) * 64 + g * 4);
            o.x = f2bf(v.x); o.y = f2bf(v.y); o.z = f2bf(v.z); o.w = f2bf(v.w);
        }
        *(ushort4*)(xbf + ((size_t)b * PS + p) * 64 + g * 4) = o;
    } else {
        const int id = (bid - 4224) * 256 + threadIdx.x;   // 327,680 total
        if (id < 262144) {                                 // A: 512x512
            const int r = id >> 9, c = id & 511;
            const u16 v = f2bf(A[id]);
            Ap0[id] = v;
            ApT0[(size_t)c * 512 + r] = v;
        } else if (id < 262144 + 32768) {                  // B: 512x64 -> B^T
            const int i = id - 262144;
            const int k = i >> 6, c = i & 63;
            BT[(size_t)c * 512 + k] = f2bf(B[i]);
        } else if (id < 262144 + 65536) {                  // C: 64x512 -> W_0
            const int i = id - 262144 - 32768;
            Wall[i] = f2bf(C[i]);
        }
    }
}

// ---------------------------------------------------------------------------
// gemm_tile64: one 64(M)x64(N) output tile, K = 512, bf16 in / fp32 acc /
// bf16 out. apM already offset to this tile's first row. bT is B^T
// ([N_total][512]); n0 selects the 64-col slice. Optional row-major out
// (oRM, already row-offset) and transposed out (oT with absolute row rowT).
// block = 256 (4 waves x 16 rows). Layouts verified in round 1.
// ---------------------------------------------------------------------------
__device__ __forceinline__ void gemm_tile64(const u16* __restrict__ apM, int lda,
                                            const u16* __restrict__ bT, int ldbt, int n0,
                                            u16* __restrict__ oRM, int ldo,
                                            u16* __restrict__ oT, int ldoT, int rowT)
{
    const int tid = threadIdx.x;
    const int w = tid >> 6, l = tid & 63;
    const int lr = l & 15, q8 = (l >> 4) * 8;

    const u16* ap  = apM + (size_t)(w * 16 + lr) * lda + q8;
    const u16* bp0 = bT  + (size_t)(n0 + lr) * ldbt + q8;

    f32x4 acc[4];
    const f32x4 zero = {0.f, 0.f, 0.f, 0.f};
    #pragma unroll
    for (int nt = 0; nt < 4; ++nt) acc[nt] = zero;

    #pragma unroll 4
    for (int ks = 0; ks < 16; ++ks) {
        const bf16x8 a = *(const bf16x8*)(ap + ks * 32);
        #pragma unroll
        for (int nt = 0; nt < 4; ++nt) {
            const bf16x8 bfr = *(const bf16x8*)(bp0 + (size_t)nt * 16 * ldbt + ks * 32);
            acc[nt] = __builtin_amdgcn_mfma_f32_16x16x32_bf16(a, bfr, acc[nt], 0, 0, 0);
        }
    }

    const int rr = (l >> 4) * 4;    // C/D: row = (lane>>4)*4 + reg, col = lane&15
    #pragma unroll
    for (int nt = 0; nt < 4; ++nt) {
        const int col = n0 + nt * 16 + lr;
        if (oRM) {
            #pragma unroll
            for (int r = 0; r < 4; ++r)
                oRM[(size_t)(w * 16 + rr + r) * ldo + col] = f2bf(acc[nt][r]);
        }
        if (oT) {
            ushort4 pk;
            pk.x = f2bf(acc[nt][0]); pk.y = f2bf(acc[nt][1]);
            pk.z = f2bf(acc[nt][2]); pk.w = f2bf(acc[nt][3]);
            *(ushort4*)(oT + (size_t)col * ldoT + rowT + w * 16 + rr) = pk;
        }
    }
}

// ---------------------------------------------------------------------------
// level_kernel: one doubling level of the W-chain, expansion + squaring fused
// into ONE launch (both consume only A^h / W[0:h), both produced earlier).
//   blockIdx.y <  nexp : W[h+by] = W[by] @ A^h           (64 rows per lag)
//   blockIdx.y >= nexp : A^{2h}[j*64 tile] = A^h @ A^h   (RM + T outputs)
// grid = (8, nexp [+8]).
// ---------------------------------------------------------------------------
__global__ __launch_bounds__(256, 1) void level_kernel(u16* __restrict__ Wall,
                                                       const u16* __restrict__ Ap,
                                                       const u16* __restrict__ ApT,
                                                       u16* __restrict__ ApN,
                                                       u16* __restrict__ ApTN,
                                                       int h, int nexp)
{
    const int n0 = blockIdx.x * 64;
    const int by = blockIdx.y;
    if (by < nexp) {
        gemm_tile64(Wall + (size_t)by * 64 * NS, NS, ApT, NS, n0,
                    Wall + (size_t)(h + by) * 64 * NS, NS, nullptr, 0, 0);
    } else {
        const int j = by - nexp;
        gemm_tile64(Ap + (size_t)j * 64 * NS, NS, ApT, NS, n0,
                    ApN + (size_t)j * 64 * NS, NS, ApTN, NS, j * 64);
    }
}

// ---------------------------------------------------------------------------
// gfinal_kernel: Gtmp[m*64+o][i] = (W_m @ B)[o][i] = G_m[o][i]. grid (1,128).
// ---------------------------------------------------------------------------
__global__ __launch_bounds__(256, 1) void gfinal_kernel(const u16* __restrict__ Wall,
                                                        const u16* __restrict__ BT,
                                                        u16* __restrict__ Gtmp)
{
    gemm_tile64(Wall + (size_t)blockIdx.y * 64 * NS, NS, BT, NS, 0,
                Gtmp + (size_t)blockIdx.y * 64 * 64, 64, nullptr, 0, 0);
}

// ---------------------------------------------------------------------------
// repack_g: Gtmp[(m*64+o)][i] -> Gsw in exact B-fragment order:
// frag fi = m*8 + ks*4 + nt; lane l holds G_m[o = nt*16+(l&15)]
// [i = ks*32+(l>>4)*8+j], j=0..7. Folds D into the lag-0 kernel.
// ---------------------------------------------------------------------------
__global__ __launch_bounds__(256) void repack_g(const u16* __restrict__ Gtmp,
                                                const float* __restrict__ D,
                                                u16* __restrict__ Gsw)
{
    const int id = blockIdx.x * 256 + threadIdx.x;  // 128*8*64 = 65,536
    const int l  = id & 63;
    const int fi = id >> 6;
    const int m  = fi >> 3;
    const int ks = (fi >> 2) & 1;
    const int nt = fi & 3;
    const int o  = nt * 16 + (l & 15);
    const int q8 = (l >> 4) * 8;

    u16 v[8];
    #pragma unroll
    for (int j = 0; j < 8; ++j) {
        const int i = ks * 32 + q8 + j;
        u16 g = Gtmp[(size_t)(m * 64 + o) * 64 + i];
        if (m == 0) g = f2bf(bf2f(g) + D[o * 64 + i]);
        v[j] = g;
    }
    ushort4* dst = (ushort4*)(Gsw + (size_t)id * 8);
    ushort4 p0; p0.x = v[0]; p0.y = v[1]; p0.z = v[2]; p0.w = v[3];
    ushort4 p1; p1.x = v[4]; p1.y = v[5]; p1.z = v[6]; p1.w = v[7];
    dst[0] = p0; dst[1] = p1;
}

// ---------------------------------------------------------------------------
// conv_kernel: y[b, t0+tau, o] = sum_{m<128} sum_i G_m[o][i] x[t0+tau-m][i]
// Grid (32 time-tiles, 16 batches) = 512 blocks -> 2 blocks/CU (occupancy fix
// vs round 1's 256 blocks = 1/CU). 256 threads = 4 waves x 32 rows each.
// X tile (128 rows + 127 halo) in LDS, stride 72 u16. G fragments streamed
// from L1/L2 (same addresses in all 4 waves) with 1-lag register prefetch.
// ---------------------------------------------------------------------------
__global__ __launch_bounds__(256, 2) void conv_kernel(const u16* __restrict__ xbf,
                                                      const u16* __restrict__ gsw,
                                                      float* __restrict__ y)
{
    __shared__ u16 Xs[XROWS * XSTR];   // 36,720 B -> >=2 blocks/CU

    const int tid = threadIdx.x;
    const int b  = blockIdx.y;
    const int t0 = blockIdx.x * CTILE;

    // Stage padded rows [t0+1 .. t0+255] (= times t0-127 .. t0+127) into LDS.
    {
        const int g = tid & 7;
        int r = tid >> 3;
        const u16* src = xbf + ((size_t)b * PS + t0 + 1) * 64 + g * 8;
        #pragma unroll
        for (int it = 0; it < 8; ++it, r += 32) {
            if (r < XROWS) {
                const uint4 v = *(const uint4*)(src + (size_t)r * 64);
                *(uint4*)&Xs[r * XSTR + g * 8] = v;
            }
        }
    }
    __syncthreads();

    const int w    = tid >> 6;
    const int l    = tid & 63;
    const int lr   = l & 15;
    const int q8   = (l >> 4) * 8;
    const int wrow = w * 32;

    const uint4* gp = (const uint4*)gsw + l;
    uint4 bn[8];
    #pragma unroll
    for (int f = 0; f < 8; ++f) bn[f] = gp[f * 64];

    f32x4 acc[2][4];
    const f32x4 zero = {0.f, 0.f, 0.f, 0.f};
    #pragma unroll
    for (int mt = 0; mt < 2; ++mt)
        #pragma unroll
        for (int nt = 0; nt < 4; ++nt) acc[mt][nt] = zero;

    #pragma unroll 2
    for (int m = 0; m < TLAG; ++m) {
        bf16x8 bc[8];
        #pragma unroll
        for (int f = 0; f < 8; ++f) bc[f] = __builtin_bit_cast(bf16x8, bn[f]);
        if (m < TLAG - 1) {
            const uint4* gn = gp + (size_t)(m + 1) * 512;
            #pragma unroll
            for (int f = 0; f < 8; ++f) bn[f] = gn[f * 64];
        }

        const int rbase = wrow + lr + (TLAG - 1) - m;
        bf16x8 a[2][2];
        #pragma unroll
        for (int mt = 0; mt < 2; ++mt)
            #pragma unroll
            for (int ks = 0; ks < 2; ++ks)
                a[mt][ks] = *(const bf16x8*)&Xs[(rbase + mt * 16) * XSTR + ks * 32 + q8];

        #pragma unroll
        for (int ks = 0; ks < 2; ++ks)
            #pragma unroll
            for (int mt = 0; mt < 2; ++mt)
                #pragma unroll
                for (int nt = 0; nt < 4; ++nt)
                    acc[mt][nt] = __builtin_amdgcn_mfma_f32_16x16x32_bf16(
                        a[mt][ks], bc[ks * 4 + nt], acc[mt][nt], 0, 0, 0);
    }

    // Epilogue: C/D layout col = lane&15 (out-feature), row = (lane>>4)*4+reg (time).
    const int rr = (l >> 4) * 4;
    #pragma unroll
    for (int mt = 0; mt < 2; ++mt) {
        #pragma unroll
        for (int nt = 0; nt < 4; ++nt) {
            const int t = t0 + wrow + mt * 16 + rr;
            const int o = nt * 16 + lr;
            float* yp = y + ((size_t)b * SEQ + t) * 64 + o;
            #pragma unroll
            for (int r = 0; r < 4; ++r) yp[(size_t)r * 64] = acc[mt][nt][r];
        }
    }
}

// ---------------------------------------------------------------------------
// Workspace layout (bytes, 16-aligned):
//   0         xbf    8,650,752   (16 x 4224 x 64 bf16)
//   8650752   Ap0      524,288   (A^h row-major, ping)
//   9175040   Ap1      524,288   (pong)
//   9699328   ApT0     524,288   (A^h transposed, ping)
//  10223616   ApT1     524,288   (pong)
//  10747904   BT        65,536   (B^T [64][512])
//  10813440   Wall   8,388,608   ([128*64][512]: row m*64+o = W_m[o][:] = (C A^m)[o][:])
//  19202048   Gtmp   1,048,576   ([128*64][64]: row m*64+o, col i = G_m[o][i])
//  20250624   Gsw    1,048,576   (B-fragment-swizzled conv kernels)
//  total: 21,299,200
// ---------------------------------------------------------------------------
extern "C" void kernel_launch(void* const* d_in, const int* in_sizes, int n_in,
                              void* d_out, int out_size, void* d_ws, size_t ws_size,
                              hipStream_t stream)
{
    const float* x = (const float*)d_in[0];
    const float* A = (const float*)d_in[1];
    const float* B = (const float*)d_in[2];
    const float* C = (const float*)d_in[3];
    const float* D = (const float*)d_in[4];
    float* y = (float*)d_out;

    char* w = (char*)d_ws;
    u16* xbf    = (u16*)(w + 0);
    u16* Ap[2]  = { (u16*)(w + 8650752),  (u16*)(w + 9175040) };
    u16* ApT[2] = { (u16*)(w + 9699328),  (u16*)(w + 10223616) };
    u16* BT     = (u16*)(w + 10747904);
    u16* Wall   = (u16*)(w + 10813440);
    u16* Gtmp   = (u16*)(w + 19202048);
    u16* Gsw    = (u16*)(w + 20250624);

    prep_all<<<5504, 256, 0, stream>>>(x, A, B, C, xbf, Ap[0], ApT[0], BT, Wall);

    // W-chain doubling: 7 dependent launches for lags [0,128).
    int h = 1, cur = 0;
    while (h < TLAG) {
        const int nexp = (h < TLAG - h) ? h : (TLAG - h);
        const int do_sq = (2 * h < TLAG) ? 1 : 0;
        dim3 grid(8, nexp + (do_sq ? 8 : 0));
        level_kernel<<<grid, 256, 0, stream>>>(Wall, Ap[cur], ApT[cur],
                                               Ap[cur ^ 1], ApT[cur ^ 1], h, nexp);
        if (do_sq) cur ^= 1;
        h += nexp;
    }

    gfinal_kernel<<<dim3(1, TLAG), 256, 0, stream>>>(Wall, BT, Gtmp);
    repack_g<<<256, 256, 0, stream>>>(Gtmp, D, Gsw);
    conv_kernel<<<dim3(SEQ / CTILE, BATCH), 256, 0, stream>>>(xbf, Gsw, y);
}